// Round 15
// baseline (652.625 us; speedup 1.0000x reference)
//
#include <hip/hip_runtime.h>
#include <hip/hip_bf16.h>

// CausalWhisperAttention on MI355X (gfx950)
// B=4, T=1500, D=1024, H=16, hd=64. Mask is a prefix mask:
//   row i attends keys j < L(i) = min(T, max(100*(i/100+1), i+51))

typedef unsigned short u16;
typedef unsigned int   u32;
typedef unsigned long long u64;
typedef __attribute__((ext_vector_type(8))) short bf16x8;
typedef __attribute__((ext_vector_type(4))) float f32x4;

typedef const __attribute__((address_space(1))) u32 gu32;
typedef __attribute__((address_space(3))) u32 lu32;

__device__ __forceinline__ void load_lds16(void* lds, const void* g) {
    __builtin_amdgcn_global_load_lds((gu32*)g, (lu32*)lds, 16, 0, 0);
}

__device__ __forceinline__ u16 f2bf(float x) {
    u32 u = __builtin_bit_cast(u32, x);
    u = (u + 0x7fffu + ((u >> 16) & 1u)) >> 16;   // RNE
    return (u16)u;
}

// packed f32x2 -> bf16x2 via HIP intrinsic (compiler-chosen operand order)
__device__ __forceinline__ u32 pkbf(float a, float b) {
    __hip_bfloat162 t = __float22bfloat162_rn(float2{a, b});
    u32 r;
    __builtin_memcpy(&r, &t, 4);
    return r;
}

__device__ __forceinline__ float fexp2(float x) {
#if __has_builtin(__builtin_amdgcn_exp2f)
    return __builtin_amdgcn_exp2f(x);
#else
    return exp2f(x);
#endif
}

#define NTOK 6000
// Q scale: (1/8) * log2(e) -- scores come out in log2 domain (exp2 softmax)
#define QSCALE 0.18033688011112042f

// ---- convert hidden_states fp32 -> bf16 ----
__global__ __launch_bounds__(256) void wa_cvt_x(const float* __restrict__ X,
                                                u16* __restrict__ Xb) {
    size_t i = ((size_t)blockIdx.x * 256 + threadIdx.x) * 4;
    if (i >= (size_t)6144000) return;
    float4 v = *(const float4*)(X + i);
    u64 p = (u64)f2bf(v.x) | ((u64)f2bf(v.y) << 16)
          | ((u64)f2bf(v.z) << 32) | ((u64)f2bf(v.w) << 48);
    *(u64*)(Xb + i) = p;
}

// ---- transpose + convert weights: Wt[n][k] = W[k][n] (bf16) ----
__global__ __launch_bounds__(256) void wa_pack_w(const float* __restrict__ Wq,
                                                 const float* __restrict__ Wk,
                                                 const float* __restrict__ Wv,
                                                 const float* __restrict__ Wo,
                                                 u16* __restrict__ Wt,
                                                 u16* __restrict__ Wto) {
    __shared__ float tile[64][65];
    const int n0 = blockIdx.x * 64;
    const int k0 = blockIdx.y * 64;
    const float* src; u16* dst; int cn;
    if (n0 < 3072) {
        int sel = n0 >> 10;
        src = (sel == 0) ? Wq : ((sel == 1) ? Wk : Wv);
        cn = n0 & 1023;
        dst = Wt + (size_t)n0 * 1024;
    } else {
        src = Wo; cn = n0 - 3072;
        dst = Wto + (size_t)(n0 - 3072) * 1024;
    }
    const int t = threadIdx.x;
    #pragma unroll
    for (int i = 0; i < 16; i++) {
        int idx = t + i * 256;
        int r = idx >> 6, c = idx & 63;
        tile[r][c] = src[(size_t)(k0 + r) * 1024 + cn + c];
    }
    __syncthreads();
    #pragma unroll
    for (int i = 0; i < 16; i++) {
        int idx = t + i * 256;
        int nr = idx >> 6, kc = idx & 63;
        dst[(size_t)nr * 1024 + k0 + kc] = f2bf(tile[kc][nr]);
    }
}

// ---- 256x256 QKV GEMM, 16 waves x (64x64 acc[4][4]) ----
// R12-R14: 512-thread + acc[8][4] spills (cap pinned at 128 VGPR). This
// keeps R6's proven per-wave codegen (~108 VGPR < 128 = the mandatory cap
// for a 1024-thread block) and scales WAVES instead: 16 waves, 4m x 4n.
// Staged traffic halves vs 128^2 (577 -> 288 MB); intensity 64 -> 128 FLOP/B.
// XCD-bijective grid (288 = 8 x 36): same-M blocks share A-panel in L2.
__global__ __launch_bounds__(1024) void wa_gemm0(
        const u16* __restrict__ A, const u16* __restrict__ Bt,
        const float* __restrict__ bq, const float* __restrict__ bv,
        u16* __restrict__ Qb, u16* __restrict__ Kb, u16* __restrict__ Vt) {
    __shared__ u16 As[2][256 * 32];
    __shared__ u16 Bs[2][256 * 32];
    const int tid = threadIdx.x;
    const int wave = tid >> 6, lane = tid & 63;
    const int wm = wave >> 2, wn = wave & 3;       // 4m x 4n wave grid
    const int r = lane & 15, g = lane >> 4;
    // bijective XCD grid: bid -> (m,n); 288 blocks = 8 XCD x (3 M x 12 N)
    const int bid = blockIdx.x;
    const int xcd = bid & 7, loc = bid >> 3;       // loc in 0..35
    const int mt = xcd * 3 + loc / 12;             // 0..23
    const int nt = loc % 12;                       // 0..11
    const int m0 = mt * 256, n0 = nt * 256;
    const bool swp = (n0 < 2048);                  // Q/K swapped, V normal

    const f32x4 z4 = {0.f, 0.f, 0.f, 0.f};
    f32x4 acc[4][4];
    #pragma unroll
    for (int i = 0; i < 4; i++)
        #pragma unroll
        for (int j = 0; j < 4; j++)
            acc[i][j] = z4;

    // staging: thread t covers row tid>>2 (0..255), 8 cols at (tid&3)*8.
    // LDS linear addr = wave*1024 + lane*16 == row-major [256][32] layout.
    const int srow = tid >> 2;
    const int scol = (tid & 3) * 8;
    const u16* aSrc = A + (size_t)(m0 + srow) * 1024 + scol;
    const u16* bSrc = Bt + (size_t)(n0 + srow) * 1024 + scol;

#define GSTAGE(K0, BUF) do {                                                  \
        load_lds16((char*)As[BUF] + wave * 1024, aSrc + (K0));                \
        load_lds16((char*)Bs[BUF] + wave * 1024, bSrc + (K0));                \
    } while (0)

    GSTAGE(0, 0);
    __syncthreads();                               // tile 0 ready
    int cur = 0;

    for (int k0 = 0; k0 < 1024; k0 += 32) {
        if (k0 + 32 < 1024) GSTAGE(k0 + 32, cur ^ 1);   // prefetch in flight
        bf16x8 a[4], b[4];
        #pragma unroll
        for (int i = 0; i < 4; i++)
            a[i] = *(const bf16x8*)&As[cur][(wm * 64 + i * 16 + r) * 32 + g * 8];
        #pragma unroll
        for (int j = 0; j < 4; j++)
            b[j] = *(const bf16x8*)&Bs[cur][(wn * 64 + j * 16 + r) * 32 + g * 8];
        if (swp) {
            #pragma unroll
            for (int i = 0; i < 4; i++)
                #pragma unroll
                for (int j = 0; j < 4; j++)
                    acc[i][j] = __builtin_amdgcn_mfma_f32_16x16x32_bf16(b[j], a[i], acc[i][j], 0, 0, 0);
        } else {
            #pragma unroll
            for (int i = 0; i < 4; i++)
                #pragma unroll
                for (int j = 0; j < 4; j++)
                    acc[i][j] = __builtin_amdgcn_mfma_f32_16x16x32_bf16(a[i], b[j], acc[i][j], 0, 0, 0);
        }
        __syncthreads();                           // prefetch landed; bufs free
        cur ^= 1;
    }
#undef GSTAGE

    const int sel = n0 >> 10;                      // 0=Q, 1=K, 2=V
    if (sel < 2) {
        // swapped: lane col = token (r), reg axis = 4 contiguous dims
        #pragma unroll
        for (int i = 0; i < 4; i++) {
            int gm = m0 + wm * 64 + i * 16 + r;
            if (gm >= NTOK) continue;
            int bb = gm / 1500, tt = gm - bb * 1500;
            #pragma unroll
            for (int j = 0; j < 4; j++) {
                int w0 = (n0 & 1023) + wn * 64 + j * 16 + g * 4;
                int h = w0 >> 6, d0 = w0 & 63;
                u16* dst = (sel == 0 ? Qb : Kb)
                         + ((size_t)(bb * 16 + h) * 1500 + tt) * 64 + d0;
                u64 pk;
                if (sel == 0) {
                    float4 bqv = *(const float4*)(bq + w0);
                    pk = (u64)f2bf((acc[i][j][0] + bqv.x) * QSCALE)
                       | ((u64)f2bf((acc[i][j][1] + bqv.y) * QSCALE) << 16)
                       | ((u64)f2bf((acc[i][j][2] + bqv.z) * QSCALE) << 32)
                       | ((u64)f2bf((acc[i][j][3] + bqv.w) * QSCALE) << 48);
                } else {
                    pk = (u64)f2bf(acc[i][j][0])
                       | ((u64)f2bf(acc[i][j][1]) << 16)
                       | ((u64)f2bf(acc[i][j][2]) << 32)
                       | ((u64)f2bf(acc[i][j][3]) << 48);
                }
                *(u64*)dst = pk;
            }
        }
    } else {
        // normal: lane col = v-dim (r), reg axis = 4 contiguous tokens
        #pragma unroll
        for (int j = 0; j < 4; j++) {
            int gn = n0 + wn * 64 + j * 16 + r;
            int w = gn & 1023;
            int h = w >> 6, d = w & 63;
            float bias = bv[w];
            #pragma unroll
            for (int i = 0; i < 4; i++) {
                int gm0 = m0 + wm * 64 + i * 16 + g * 4;
                if (gm0 >= NTOK) continue;          // 6000,1500 both %4==0
                int bb = gm0 / 1500, tt0 = gm0 - bb * 1500;
                u64 pk = (u64)f2bf(acc[i][j][0] + bias)
                       | ((u64)f2bf(acc[i][j][1] + bias) << 16)
                       | ((u64)f2bf(acc[i][j][2] + bias) << 32)
                       | ((u64)f2bf(acc[i][j][3] + bias) << 48);
                *(u64*)(Vt + ((size_t)(bb * 16 + h) * 64 + d) * 1504 + tt0) = pk;
            }
        }
    }
}

// ---- 128x128 out-proj GEMM (R6-proven): out = A * Wto^T + bo ----
__global__ __launch_bounds__(256) void wa_gemm1(
        const u16* __restrict__ A, const u16* __restrict__ Bt,
        const float* __restrict__ bo, float* __restrict__ outF) {
    __shared__ u16 As[2][128 * 32];
    __shared__ u16 Bs[2][128 * 32];
    const int tid = threadIdx.x;
    const int wave = tid >> 6, lane = tid & 63;
    const int wm = wave >> 1, wn = wave & 1;
    const int r = lane & 15, g = lane >> 4;
    const int m0 = blockIdx.x * 128, n0 = blockIdx.y * 128;

    const f32x4 z4 = {0.f, 0.f, 0.f, 0.f};
    f32x4 acc[4][4];
    #pragma unroll
    for (int i = 0; i < 4; i++)
        #pragma unroll
        for (int j = 0; j < 4; j++)
            acc[i][j] = z4;

    const int srow = wave * 32 + (lane >> 2);
    const int scol = (lane & 3) * 8;
    const u16* aSrc = A + (size_t)(m0 + srow) * 1024 + scol;
    const u16* bSrc = Bt + (size_t)(n0 + srow) * 1024 + scol;

#define GSTAGE(K0, BUF) do {                                                  \
        load_lds16((char*)As[BUF] + wave * 2048,        aSrc + (K0));         \
        load_lds16((char*)As[BUF] + wave * 2048 + 1024, aSrc + 16 * 1024 + (K0)); \
        load_lds16((char*)Bs[BUF] + wave * 2048,        bSrc + (K0));         \
        load_lds16((char*)Bs[BUF] + wave * 2048 + 1024, bSrc + 16 * 1024 + (K0)); \
    } while (0)

    GSTAGE(0, 0);
    __syncthreads();
    int cur = 0;

    for (int k0 = 0; k0 < 1024; k0 += 32) {
        if (k0 + 32 < 1024) GSTAGE(k0 + 32, cur ^ 1);
        bf16x8 a[4], b[4];
        #pragma unroll
        for (int i = 0; i < 4; i++)
            a[i] = *(const bf16x8*)&As[cur][(wm * 64 + i * 16 + r) * 32 + g * 8];
        #pragma unroll
        for (int j = 0; j < 4; j++)
            b[j] = *(const bf16x8*)&Bs[cur][(wn * 64 + j * 16 + r) * 32 + g * 8];
        #pragma unroll
        for (int i = 0; i < 4; i++)
            #pragma unroll
            for (int j = 0; j < 4; j++)
                acc[i][j] = __builtin_amdgcn_mfma_f32_16x16x32_bf16(b[j], a[i], acc[i][j], 0, 0, 0);
        __syncthreads();
        cur ^= 1;
    }
#undef GSTAGE

    // swapped: lane col = token, reg axis = 4 contiguous out-cols
    #pragma unroll
    for (int i = 0; i < 4; i++) {
        int gm = m0 + wm * 64 + i * 16 + r;
        if (gm >= NTOK) continue;
        #pragma unroll
        for (int j = 0; j < 4; j++) {
            int gn0 = n0 + wn * 64 + j * 16 + g * 4;
            float4 bov = *(const float4*)(bo + gn0);
            float4 v = {acc[i][j][0] + bov.x, acc[i][j][1] + bov.y,
                        acc[i][j][2] + bov.z, acc[i][j][3] + bov.w};
            *(float4*)(outF + (size_t)gm * 1024 + gn0) = v;
        }
    }
}

// ---- fused flash attention over the prefix mask ----
// R6 structure (double-buffered K/V prefetch, XCD swizzle) + exp2-domain
// softmax + compiler-packed bf16 converts (R11-proven).
__global__ __launch_bounds__(256) void wa_attn(const u16* __restrict__ Qb,
                                               const u16* __restrict__ Kb,
                                               const u16* __restrict__ Vt,
                                               u16* __restrict__ Ob) {
    __shared__ u16 Ks[2][64 * 64];
    __shared__ u16 Vs[2][64 * 64];
    __shared__ u16 Ps[4][16 * 64];
    const int tid = threadIdx.x, wave = tid >> 6, lane = tid & 63;
    const int q = lane & 15, g = lane >> 4;
    // bijective XCD swizzle: plane % 8 == blockIdx.x % 8
    const int bid = blockIdx.x;
    const int qt = (bid >> 3) % 24;
    const int plane = ((bid >> 3) / 24) * 8 + (bid & 7);
    const int h = plane & 15, b = plane >> 4;

    const int qr = qt * 64 + wave * 16 + q;
    const int qc = qr < 1500 ? qr : 1499;
    int Lq = (qr / 100 + 1) * 100;
    { int la = qr + 51; if (la > Lq) Lq = la; }
    if (Lq > 1500) Lq = 1500;
    int qmax = qt * 64 + 63; if (qmax > 1499) qmax = 1499;
    int Lb = (qmax / 100 + 1) * 100;
    { int lb2 = qmax + 51; if (lb2 > Lb) Lb = lb2; }
    if (Lb > 1500) Lb = 1500;
    const int ntiles = (Lb + 63) >> 6;

    const u16* qp = Qb + ((size_t)plane * 1500 + qc) * 64 + g * 8;
    const bf16x8 qa0 = *(const bf16x8*)qp;
    const bf16x8 qa1 = *(const bf16x8*)(qp + 32);

    const f32x4 z4 = {0.f, 0.f, 0.f, 0.f};
    f32x4 accO[4];
    #pragma unroll
    for (int dt = 0; dt < 4; dt++) accO[dt] = z4;
    float m_run = -3.0e38f, l_run = 0.f;

    const int sRow = wave * 16 + (lane >> 3);
    const int sO = (lane & 7) * 16;
    const u16* kBase = Kb + (size_t)plane * 1500 * 64;
    const u16* vBase = Vt + (size_t)plane * 64 * 1504;

#define STAGE(J0, BUF) do {                                              \
        _Pragma("unroll")                                                \
        for (int i_ = 0; i_ < 2; i_++) {                                 \
            int row_ = sRow + i_ * 8;                                    \
            int so_ = sO ^ ((row_ & 7) << 4);                            \
            int key_ = (J0) + row_; if (key_ > 1499) key_ = 1499;        \
            load_lds16((char*)Ks[BUF] + wave * 2048 + i_ * 1024,         \
                       kBase + (size_t)key_ * 64 + (so_ >> 1));          \
            int vc_ = (J0) + (so_ >> 1); if (vc_ > 1496) vc_ = 1496;     \
            load_lds16((char*)Vs[BUF] + wave * 2048 + i_ * 1024,         \
                       vBase + (size_t)row_ * 1504 + vc_);               \
        } } while (0)

    STAGE(0, 0);
    __syncthreads();                               // drains vmcnt: tile 0 ready
    int cur = 0;

    for (int ti = 0; ti < ntiles; ti++) {
        const int j0 = ti << 6;
        if (ti + 1 < ntiles) STAGE(j0 + 64, cur ^ 1);   // prefetch in flight

        const char* kb = (const char*)Ks[cur];
        const char* vb = (const char*)Vs[cur];

        // S^T: mfma(K, Q) -> [key][q]; scores in log2 domain (QSCALE)
        f32x4 st[4];
        #pragma unroll
        for (int t = 0; t < 4; t++) {
            f32x4 s = z4;
            #pragma unroll
            for (int ks = 0; ks < 2; ks++) {
                int krow = t * 16 + q;
                int cb = (ks * 64 + g * 16) ^ ((krow & 7) << 4);
                bf16x8 kf = *(const bf16x8*)(kb + krow * 128 + cb);
                s = __builtin_amdgcn_mfma_f32_16x16x32_bf16(kf, ks ? qa1 : qa0, s, 0, 0, 0);
            }
            st[t] = s;
        }

        // mask + online softmax (exp2 domain)
        float p[16];
        float mt = -3.0e38f;
        #pragma unroll
        for (int t = 0; t < 4; t++)
            #pragma unroll
            for (int e = 0; e < 4; e++) {
                int key = j0 + t * 16 + g * 4 + e;
                float sv = (key < Lq) ? st[t][e] : -3.0e38f;
                p[t * 4 + e] = sv;
                mt = fmaxf(mt, sv);
            }
        mt = fmaxf(mt, __shfl_xor(mt, 16));
        mt = fmaxf(mt, __shfl_xor(mt, 32));
        float m_new = fmaxf(m_run, mt);
        float resc = fexp2(m_run - m_new);
        float sum = 0.f;
        #pragma unroll
        for (int i = 0; i < 16; i++) { p[i] = fexp2(p[i] - m_new); sum += p[i]; }
        sum += __shfl_xor(sum, 16);
        sum += __shfl_xor(sum, 32);
        l_run = l_run * resc + sum;
        m_run = m_new;
        #pragma unroll
        for (int dt = 0; dt < 4; dt++) accO[dt] *= resc;

        // P -> per-wave swizzled LDS [q][key] (bf16, compiler-packed cvt)
        {
            char* pw = (char*)Ps[wave];
            const int sw = (q & 7) << 4;
            #pragma unroll
            for (int t = 0; t < 4; t++) {
                u32 lo = pkbf(p[t * 4 + 0], p[t * 4 + 1]);
                u32 hi = pkbf(p[t * 4 + 2], p[t * 4 + 3]);
                int c0 = t * 32 + g * 8;
                *(u32*)(pw + q * 128 + ((c0)     ^ sw)) = lo;
                *(u32*)(pw + q * 128 + ((c0 + 4) ^ sw)) = hi;
            }
        }
        asm volatile("" ::: "memory");

        // PV: mfma(V^T, P^T) -> O^T
        #pragma unroll
        for (int s2 = 0; s2 < 2; s2++) {
            int cb = s2 * 64 + g * 16;
            bf16x8 pf = *(const bf16x8*)((const char*)Ps[wave] + q * 128 + (cb ^ ((q & 7) << 4)));
            #pragma unroll
            for (int dt = 0; dt < 4; dt++) {
                int dr = dt * 16 + q;
                bf16x8 vf = *(const bf16x8*)(vb + dr * 128 + (cb ^ ((dr & 7) << 4)));
                accO[dt] = __builtin_amdgcn_mfma_f32_16x16x32_bf16(vf, pf, accO[dt], 0, 0, 0);
            }
        }

        __syncthreads();                           // prefetch landed; bufs free
        cur ^= 1;
    }
#undef STAGE

    float inv = 1.0f / l_run;
    if (qr < 1500) {
        u16* op = Ob + ((size_t)(b * 1500 + qr)) * 1024 + h * 64 + g * 4;
        #pragma unroll
        for (int dt = 0; dt < 4; dt++) {
            u32 lo = pkbf(accO[dt][0] * inv, accO[dt][1] * inv);
            u32 hi = pkbf(accO[dt][2] * inv, accO[dt][3] * inv);
            *(u64*)(op + dt * 16) = (u64)lo | ((u64)hi << 32);
        }
    }
}

extern "C" void kernel_launch(void* const* d_in, const int* in_sizes, int n_in,
                              void* d_out, int out_size, void* d_ws, size_t ws_size,
                              hipStream_t stream) {
    (void)in_sizes; (void)n_in; (void)out_size; (void)ws_size;
    const float* X  = (const float*)d_in[0];
    const float* Wq = (const float*)d_in[1];
    const float* bq = (const float*)d_in[2];
    const float* Wk = (const float*)d_in[3];
    const float* Wv = (const float*)d_in[4];
    const float* bv = (const float*)d_in[5];
    const float* Wo = (const float*)d_in[6];
    const float* bo = (const float*)d_in[7];
    float* out = (float*)d_out;

    // workspace layout (bf16 elements), total ~57.6 MB
    u16* Xb  = (u16*)d_ws;                       // [6016][1024]; reused as attn-out
    u16* Wt  = Xb  + (size_t)6016 * 1024;        // [3072][1024]
    u16* Wto = Wt  + (size_t)3072 * 1024;        // [1024][1024]
    u16* Qb  = Wto + (size_t)1024 * 1024;        // [64][1500][64]
    u16* Kb  = Qb  + (size_t)64 * 1500 * 64;     // [64][1500][64]
    u16* Vt  = Kb  + (size_t)64 * 1500 * 64;     // [64][64][1504] (+slack)

    wa_cvt_x<<<6000, 256, 0, stream>>>(X, Xb);
    wa_pack_w<<<dim3(64, 16), 256, 0, stream>>>(Wq, Wk, Wv, Wo, Wt, Wto);
    wa_gemm0<<<288, 1024, 0, stream>>>(Xb, Wt, bq, bv, Qb, Kb, Vt);
    wa_attn<<<1536, 256, 0, stream>>>(Qb, Kb, Vt, Xb);
    wa_gemm1<<<dim3(47, 8), 256, 0, stream>>>(Xb, Wto, bo, out);
}

// Round 16
// 178.583 us; speedup vs baseline: 3.6545x; 3.6545x over previous
//
#include <hip/hip_runtime.h>
#include <hip/hip_bf16.h>

// CausalWhisperAttention on MI355X (gfx950)
// B=4, T=1500, D=1024, H=16, hd=64. Mask is a prefix mask:
//   row i attends keys j < L(i) = min(T, max(100*(i/100+1), i+51))

typedef unsigned short u16;
typedef unsigned int   u32;
typedef unsigned long long u64;
typedef __attribute__((ext_vector_type(8))) short bf16x8;
typedef __attribute__((ext_vector_type(4))) float f32x4;

typedef const __attribute__((address_space(1))) u32 gu32;
typedef __attribute__((address_space(3))) u32 lu32;

__device__ __forceinline__ void load_lds16(void* lds, const void* g) {
    __builtin_amdgcn_global_load_lds((gu32*)g, (lu32*)lds, 16, 0, 0);
}

__device__ __forceinline__ u16 f2bf(float x) {
    u32 u = __builtin_bit_cast(u32, x);
    u = (u + 0x7fffu + ((u >> 16) & 1u)) >> 16;   // RNE
    return (u16)u;
}

// packed f32x2 -> bf16x2 via HIP intrinsic (compiler-chosen operand order)
__device__ __forceinline__ u32 pkbf(float a, float b) {
    __hip_bfloat162 t = __float22bfloat162_rn(float2{a, b});
    u32 r;
    __builtin_memcpy(&r, &t, 4);
    return r;
}

__device__ __forceinline__ float fexp2(float x) {
#if __has_builtin(__builtin_amdgcn_exp2f)
    return __builtin_amdgcn_exp2f(x);
#else
    return exp2f(x);
#endif
}

#define NTOK 6000
// Q scale: (1/8) * log2(e) -- scores come out in log2 domain (exp2 softmax)
#define QSCALE 0.18033688011112042f

// ---- convert hidden_states fp32 -> bf16 ----
__global__ __launch_bounds__(256) void wa_cvt_x(const float* __restrict__ X,
                                                u16* __restrict__ Xb) {
    size_t i = ((size_t)blockIdx.x * 256 + threadIdx.x) * 4;
    if (i >= (size_t)6144000) return;
    float4 v = *(const float4*)(X + i);
    u64 p = (u64)f2bf(v.x) | ((u64)f2bf(v.y) << 16)
          | ((u64)f2bf(v.z) << 32) | ((u64)f2bf(v.w) << 48);
    *(u64*)(Xb + i) = p;
}

// ---- transpose + convert weights: Wt[n][k] = W[k][n] (bf16) ----
__global__ __launch_bounds__(256) void wa_pack_w(const float* __restrict__ Wq,
                                                 const float* __restrict__ Wk,
                                                 const float* __restrict__ Wv,
                                                 const float* __restrict__ Wo,
                                                 u16* __restrict__ Wt,
                                                 u16* __restrict__ Wto) {
    __shared__ float tile[64][65];
    const int n0 = blockIdx.x * 64;
    const int k0 = blockIdx.y * 64;
    const float* src; u16* dst; int cn;
    if (n0 < 3072) {
        int sel = n0 >> 10;
        src = (sel == 0) ? Wq : ((sel == 1) ? Wk : Wv);
        cn = n0 & 1023;
        dst = Wt + (size_t)n0 * 1024;
    } else {
        src = Wo; cn = n0 - 3072;
        dst = Wto + (size_t)(n0 - 3072) * 1024;
    }
    const int t = threadIdx.x;
    #pragma unroll
    for (int i = 0; i < 16; i++) {
        int idx = t + i * 256;
        int r = idx >> 6, c = idx & 63;
        tile[r][c] = src[(size_t)(k0 + r) * 1024 + cn + c];
    }
    __syncthreads();
    #pragma unroll
    for (int i = 0; i < 16; i++) {
        int idx = t + i * 256;
        int nr = idx >> 6, kc = idx & 63;
        dst[(size_t)nr * 1024 + k0 + kc] = f2bf(tile[kc][nr]);
    }
}

// ---- bf16 GEMM 128x128 (R6/R11-proven best): C = A[M][1024] * Bt^T ----
// 256^2 condemned: toolchain caps VGPRs at 65536/blockDim (R12-R15, 4 ways),
// acc[8][4]/acc[4][4]@1024T always spill. This structure = 455 TF at our
// shape, above m102's shape-adjusted ceiling for the 2-barrier structure.
template<int EPI>
__global__ __launch_bounds__(256) void wa_gemm(
        const u16* __restrict__ A, const u16* __restrict__ Bt,
        const float* __restrict__ bq, const float* __restrict__ bv,
        u16* __restrict__ Qb, u16* __restrict__ Kb, u16* __restrict__ Vt,
        const float* __restrict__ bo, float* __restrict__ outF) {
    __shared__ u16 As[2][128 * 32];
    __shared__ u16 Bs[2][128 * 32];
    const int tid = threadIdx.x;
    const int wave = tid >> 6, lane = tid & 63;
    const int wm = wave >> 1, wn = wave & 1;
    const int r = lane & 15, g = lane >> 4;
    const int m0 = blockIdx.x * 128, n0 = blockIdx.y * 128;
    const bool swp = (EPI == 1) || (n0 < 2048);   // block-uniform

    const f32x4 z4 = {0.f, 0.f, 0.f, 0.f};
    f32x4 acc[4][4];
    #pragma unroll
    for (int i = 0; i < 4; i++)
        #pragma unroll
        for (int j = 0; j < 4; j++)
            acc[i][j] = z4;

    const int srow = wave * 32 + (lane >> 2);
    const int scol = (lane & 3) * 8;
    const u16* aSrc = A + (size_t)(m0 + srow) * 1024 + scol;
    const u16* bSrc = Bt + (size_t)(n0 + srow) * 1024 + scol;

#define GSTAGE(K0, BUF) do {                                                  \
        load_lds16((char*)As[BUF] + wave * 2048,        aSrc + (K0));         \
        load_lds16((char*)As[BUF] + wave * 2048 + 1024, aSrc + 16 * 1024 + (K0)); \
        load_lds16((char*)Bs[BUF] + wave * 2048,        bSrc + (K0));         \
        load_lds16((char*)Bs[BUF] + wave * 2048 + 1024, bSrc + 16 * 1024 + (K0)); \
    } while (0)

    GSTAGE(0, 0);
    __syncthreads();                               // tile 0 ready
    int cur = 0;

    for (int k0 = 0; k0 < 1024; k0 += 32) {
        if (k0 + 32 < 1024) GSTAGE(k0 + 32, cur ^ 1);   // prefetch in flight
        bf16x8 a[4], b[4];
        #pragma unroll
        for (int i = 0; i < 4; i++)
            a[i] = *(const bf16x8*)&As[cur][(wm * 64 + i * 16 + r) * 32 + g * 8];
        #pragma unroll
        for (int j = 0; j < 4; j++)
            b[j] = *(const bf16x8*)&Bs[cur][(wn * 64 + j * 16 + r) * 32 + g * 8];
        if (swp) {
            #pragma unroll
            for (int i = 0; i < 4; i++)
                #pragma unroll
                for (int j = 0; j < 4; j++)
                    acc[i][j] = __builtin_amdgcn_mfma_f32_16x16x32_bf16(b[j], a[i], acc[i][j], 0, 0, 0);
        } else {
            #pragma unroll
            for (int i = 0; i < 4; i++)
                #pragma unroll
                for (int j = 0; j < 4; j++)
                    acc[i][j] = __builtin_amdgcn_mfma_f32_16x16x32_bf16(a[i], b[j], acc[i][j], 0, 0, 0);
        }
        __syncthreads();                           // prefetch landed; bufs free
        cur ^= 1;
    }
#undef GSTAGE

    if constexpr (EPI == 0) {
        const int sel = n0 >> 10;                 // 0=Q, 1=K, 2=V
        if (sel < 2) {
            // swapped: lane col = token (r), reg axis = 4 contiguous dims
            #pragma unroll
            for (int i = 0; i < 4; i++) {
                int gm = m0 + wm * 64 + i * 16 + r;
                if (gm >= NTOK) continue;
                int bb = gm / 1500, tt = gm - bb * 1500;
                #pragma unroll
                for (int j = 0; j < 4; j++) {
                    int w0 = (n0 & 1023) + wn * 64 + j * 16 + g * 4;
                    int h = w0 >> 6, d0 = w0 & 63;
                    u16* dst = (sel == 0 ? Qb : Kb)
                             + ((size_t)(bb * 16 + h) * 1500 + tt) * 64 + d0;
                    u64 pk;
                    if (sel == 0) {
                        float4 bqv = *(const float4*)(bq + w0);
                        pk = (u64)f2bf((acc[i][j][0] + bqv.x) * QSCALE)
                           | ((u64)f2bf((acc[i][j][1] + bqv.y) * QSCALE) << 16)
                           | ((u64)f2bf((acc[i][j][2] + bqv.z) * QSCALE) << 32)
                           | ((u64)f2bf((acc[i][j][3] + bqv.w) * QSCALE) << 48);
                    } else {
                        pk = (u64)f2bf(acc[i][j][0])
                           | ((u64)f2bf(acc[i][j][1]) << 16)
                           | ((u64)f2bf(acc[i][j][2]) << 32)
                           | ((u64)f2bf(acc[i][j][3]) << 48);
                    }
                    *(u64*)dst = pk;
                }
            }
        } else {
            // normal: lane col = v-dim (r), reg axis = 4 contiguous tokens
            #pragma unroll
            for (int j = 0; j < 4; j++) {
                int gn = n0 + wn * 64 + j * 16 + r;
                int w = gn & 1023;
                int h = w >> 6, d = w & 63;
                float bias = bv[w];
                #pragma unroll
                for (int i = 0; i < 4; i++) {
                    int gm0 = m0 + wm * 64 + i * 16 + g * 4;
                    if (gm0 >= NTOK) continue;      // 6000,1500 both %4==0
                    int bb = gm0 / 1500, tt0 = gm0 - bb * 1500;
                    u64 pk = (u64)f2bf(acc[i][j][0] + bias)
                           | ((u64)f2bf(acc[i][j][1] + bias) << 16)
                           | ((u64)f2bf(acc[i][j][2] + bias) << 32)
                           | ((u64)f2bf(acc[i][j][3] + bias) << 48);
                    *(u64*)(Vt + ((size_t)(bb * 16 + h) * 64 + d) * 1504 + tt0) = pk;
                }
            }
        }
    } else {
        // swapped: lane col = token, reg axis = 4 contiguous out-cols
        #pragma unroll
        for (int i = 0; i < 4; i++) {
            int gm = m0 + wm * 64 + i * 16 + r;
            if (gm >= NTOK) continue;
            #pragma unroll
            for (int j = 0; j < 4; j++) {
                int gn0 = n0 + wn * 64 + j * 16 + g * 4;
                float4 bov = *(const float4*)(bo + gn0);
                float4 v = {acc[i][j][0] + bov.x, acc[i][j][1] + bov.y,
                            acc[i][j][2] + bov.z, acc[i][j][3] + bov.w};
                *(float4*)(outF + (size_t)gm * 1024 + gn0) = v;
            }
        }
    }
}

// ---- fused flash attention, 8 waves x 16 q-rows = 128 q-rows/block ----
// Halves block count (1536->768) and K/V re-fetch; each wave stages 8 K-rows
// + 8 V-rows per tile; LDS 48 KB -> 3 blocks/CU (24 waves/CU vs 16 before).
// Inner math / layouts / swizzles identical to the R11-proven version.
__global__ __launch_bounds__(512) void wa_attn(const u16* __restrict__ Qb,
                                               const u16* __restrict__ Kb,
                                               const u16* __restrict__ Vt,
                                               u16* __restrict__ Ob) {
    __shared__ u16 Ks[2][64 * 64];
    __shared__ u16 Vs[2][64 * 64];
    __shared__ u16 Ps[8][16 * 64];
    const int tid = threadIdx.x, wave = tid >> 6, lane = tid & 63;
    const int q = lane & 15, g = lane >> 4;
    // bijective XCD swizzle: plane % 8 == blockIdx.x % 8 (768 = 8 x 12 x 8)
    const int bid = blockIdx.x;
    const int qt = (bid >> 3) % 12;
    const int plane = ((bid >> 3) / 12) * 8 + (bid & 7);
    const int h = plane & 15, b = plane >> 4;

    const int qr = qt * 128 + wave * 16 + q;
    const int qc = qr < 1500 ? qr : 1499;
    int Lq = (qr / 100 + 1) * 100;
    { int la = qr + 51; if (la > Lq) Lq = la; }
    if (Lq > 1500) Lq = 1500;
    int qmax = qt * 128 + 127; if (qmax > 1499) qmax = 1499;
    int Lb = (qmax / 100 + 1) * 100;
    { int lb2 = qmax + 51; if (lb2 > Lb) Lb = lb2; }
    if (Lb > 1500) Lb = 1500;
    const int ntiles = (Lb + 63) >> 6;

    const u16* qp = Qb + ((size_t)plane * 1500 + qc) * 64 + g * 8;
    const bf16x8 qa0 = *(const bf16x8*)qp;
    const bf16x8 qa1 = *(const bf16x8*)(qp + 32);

    const f32x4 z4 = {0.f, 0.f, 0.f, 0.f};
    f32x4 accO[4];
    #pragma unroll
    for (int dt = 0; dt < 4; dt++) accO[dt] = z4;
    float m_run = -3.0e38f, l_run = 0.f;

    // staging: 8 waves x 8 rows = 64 K-rows and 64 V-rows per buffer
    const int sRow = wave * 8 + (lane >> 3);
    const int sO = (lane & 7) * 16;
    const u16* kBase = Kb + (size_t)plane * 1500 * 64;
    const u16* vBase = Vt + (size_t)plane * 64 * 1504;

#define STAGE(J0, BUF) do {                                              \
        int row_ = sRow;                                                 \
        int so_ = sO ^ ((row_ & 7) << 4);                                \
        int key_ = (J0) + row_; if (key_ > 1499) key_ = 1499;            \
        load_lds16((char*)Ks[BUF] + wave * 1024,                         \
                   kBase + (size_t)key_ * 64 + (so_ >> 1));              \
        int vc_ = (J0) + (so_ >> 1); if (vc_ > 1496) vc_ = 1496;         \
        load_lds16((char*)Vs[BUF] + wave * 1024,                         \
                   vBase + (size_t)row_ * 1504 + vc_);                   \
    } while (0)

    STAGE(0, 0);
    __syncthreads();                               // drains vmcnt: tile 0 ready
    int cur = 0;

    for (int ti = 0; ti < ntiles; ti++) {
        const int j0 = ti << 6;
        if (ti + 1 < ntiles) STAGE(j0 + 64, cur ^ 1);   // prefetch in flight

        const char* kb = (const char*)Ks[cur];
        const char* vb = (const char*)Vs[cur];

        // S^T: mfma(K, Q) -> [key][q]; scores in log2 domain (QSCALE)
        f32x4 st[4];
        #pragma unroll
        for (int t = 0; t < 4; t++) {
            f32x4 s = z4;
            #pragma unroll
            for (int ks = 0; ks < 2; ks++) {
                int krow = t * 16 + q;
                int cb = (ks * 64 + g * 16) ^ ((krow & 7) << 4);
                bf16x8 kf = *(const bf16x8*)(kb + krow * 128 + cb);
                s = __builtin_amdgcn_mfma_f32_16x16x32_bf16(kf, ks ? qa1 : qa0, s, 0, 0, 0);
            }
            st[t] = s;
        }

        // mask + online softmax (exp2 domain)
        float p[16];
        float mt = -3.0e38f;
        #pragma unroll
        for (int t = 0; t < 4; t++)
            #pragma unroll
            for (int e = 0; e < 4; e++) {
                int key = j0 + t * 16 + g * 4 + e;
                float sv = (key < Lq) ? st[t][e] : -3.0e38f;
                p[t * 4 + e] = sv;
                mt = fmaxf(mt, sv);
            }
        mt = fmaxf(mt, __shfl_xor(mt, 16));
        mt = fmaxf(mt, __shfl_xor(mt, 32));
        float m_new = fmaxf(m_run, mt);
        float resc = fexp2(m_run - m_new);
        float sum = 0.f;
        #pragma unroll
        for (int i = 0; i < 16; i++) { p[i] = fexp2(p[i] - m_new); sum += p[i]; }
        sum += __shfl_xor(sum, 16);
        sum += __shfl_xor(sum, 32);
        l_run = l_run * resc + sum;
        m_run = m_new;
        #pragma unroll
        for (int dt = 0; dt < 4; dt++) accO[dt] *= resc;

        // P -> per-wave swizzled LDS [q][key] (bf16, compiler-packed cvt)
        {
            char* pw = (char*)Ps[wave];
            const int sw = (q & 7) << 4;
            #pragma unroll
            for (int t = 0; t < 4; t++) {
                u32 lo = pkbf(p[t * 4 + 0], p[t * 4 + 1]);
                u32 hi = pkbf(p[t * 4 + 2], p[t * 4 + 3]);
                int c0 = t * 32 + g * 8;
                *(u32*)(pw + q * 128 + ((c0)     ^ sw)) = lo;
                *(u32*)(pw + q * 128 + ((c0 + 4) ^ sw)) = hi;
            }
        }
        asm volatile("" ::: "memory");

        // PV: mfma(V^T, P^T) -> O^T
        #pragma unroll
        for (int s2 = 0; s2 < 2; s2++) {
            int cb = s2 * 64 + g * 16;
            bf16x8 pf = *(const bf16x8*)((const char*)Ps[wave] + q * 128 + (cb ^ ((q & 7) << 4)));
            #pragma unroll
            for (int dt = 0; dt < 4; dt++) {
                int dr = dt * 16 + q;
                bf16x8 vf = *(const bf16x8*)(vb + dr * 128 + (cb ^ ((dr & 7) << 4)));
                accO[dt] = __builtin_amdgcn_mfma_f32_16x16x32_bf16(vf, pf, accO[dt], 0, 0, 0);
            }
        }

        __syncthreads();                           // prefetch landed; bufs free
        cur ^= 1;
    }
#undef STAGE

    float inv = 1.0f / l_run;
    if (qr < 1500) {
        u16* op = Ob + ((size_t)(b * 1500 + qr)) * 1024 + h * 64 + g * 4;
        #pragma unroll
        for (int dt = 0; dt < 4; dt++) {
            u32 lo = pkbf(accO[dt][0] * inv, accO[dt][1] * inv);
            u32 hi = pkbf(accO[dt][2] * inv, accO[dt][3] * inv);
            *(u64*)(op + dt * 16) = (u64)lo | ((u64)hi << 32);
        }
    }
}

extern "C" void kernel_launch(void* const* d_in, const int* in_sizes, int n_in,
                              void* d_out, int out_size, void* d_ws, size_t ws_size,
                              hipStream_t stream) {
    (void)in_sizes; (void)n_in; (void)out_size; (void)ws_size;
    const float* X  = (const float*)d_in[0];
    const float* Wq = (const float*)d_in[1];
    const float* bq = (const float*)d_in[2];
    const float* Wk = (const float*)d_in[3];
    const float* Wv = (const float*)d_in[4];
    const float* bv = (const float*)d_in[5];
    const float* Wo = (const float*)d_in[6];
    const float* bo = (const float*)d_in[7];
    float* out = (float*)d_out;

    // workspace layout (bf16 elements), total ~57.6 MB
    u16* Xb  = (u16*)d_ws;                       // [6016][1024]; reused as attn-out
    u16* Wt  = Xb  + (size_t)6016 * 1024;        // [3072][1024]
    u16* Wto = Wt  + (size_t)3072 * 1024;        // [1024][1024]
    u16* Qb  = Wto + (size_t)1024 * 1024;        // [64][1500][64]
    u16* Kb  = Qb  + (size_t)64 * 1500 * 64;     // [64][1500][64]
    u16* Vt  = Kb  + (size_t)64 * 1500 * 64;     // [64][64][1504] (+slack)

    wa_cvt_x<<<6000, 256, 0, stream>>>(X, Xb);
    wa_pack_w<<<dim3(64, 16), 256, 0, stream>>>(Wq, Wk, Wv, Wo, Wt, Wto);
    wa_gemm<0><<<dim3(47, 24), 256, 0, stream>>>(Xb, Wt, bq, bv, Qb, Kb, Vt, nullptr, nullptr);
    wa_attn<<<768, 512, 0, stream>>>(Qb, Kb, Vt, Xb);
    wa_gemm<1><<<dim3(47, 8), 256, 0, stream>>>(Xb, Wto, nullptr, nullptr, nullptr, nullptr, nullptr, bo, out);
}